// Round 2
// baseline (6348.494 us; speedup 1.0000x reference)
//
#include <hip/hip_runtime.h>
#include <hip/hip_bf16.h>

#define TT 128
#define BB 256
#define OBSD 1024
#define FEATD 512
#define NA 15
#define DD 528
#define GG 2112   // 4*DD
#define KK 1056   // 2*DD
#define SCL 4096.f
#define INV_SCL (1.f/4096.f)

using half8 = __attribute__((ext_vector_type(8))) _Float16;
using f32x4 = __attribute__((ext_vector_type(4))) float;

__device__ __forceinline__ void split1(float v, _Float16& h, _Float16& l){
  h = (_Float16)v;
  l = (_Float16)((v - (float)h) * SCL);
}
__device__ __forceinline__ float sigf(float x){ return 1.f/(1.f + expf(-x)); }

// ---------------- prep kernels ----------------

// Concat [w_ih | w_hh] -> f16 hi/lo planes W[GG][KK]; bias = b_ih + b_hh
__global__ void k_prep_w(const float* __restrict__ wih, const float* __restrict__ whh,
                         const float* __restrict__ bih, const float* __restrict__ bhh,
                         _Float16* __restrict__ Wh, _Float16* __restrict__ Wl,
                         float* __restrict__ bias){
  const int n = GG*KK;
  for (int i = blockIdx.x*blockDim.x + threadIdx.x; i < n; i += gridDim.x*blockDim.x){
    int r = i / KK, c = i % KK;
    float v = (c < DD) ? wih[r*DD + c] : whh[r*DD + (c - DD)];
    split1(v, Wh[i], Wl[i]);
    if (i < GG) bias[i] = bih[i] + bhh[i];
  }
}

__global__ void k_conv_encw(const float* __restrict__ src,
                            _Float16* __restrict__ dh, _Float16* __restrict__ dl){
  const int n = FEATD*OBSD;
  for (int i = blockIdx.x*blockDim.x + threadIdx.x; i < n; i += gridDim.x*blockDim.x)
    split1(src[i], dh[i], dl[i]);
}

// lstm_in cols 512..527: clipped reward + one_hot(last_action), fp32
__global__ void k_fill_extra(const float* __restrict__ reward, const int* __restrict__ act,
                             float* __restrict__ lstmin){
  int row = blockIdx.x*blockDim.x + threadIdx.x;
  if (row >= TT*BB) return;
  float r = fminf(1.f, fmaxf(-1.f, reward[row]));
  float* p = lstmin + (size_t)row*DD + FEATD;
  p[0] = r;
  int a = act[row];
  #pragma unroll
  for (int i = 0; i < NA; ++i) p[1+i] = (i == a) ? 1.f : 0.f;
}

// ---------------- encoder GEMM: relu(obs @ enc_w^T + enc_b) -> lstm_in[:, 0:512] fp32 ----------------
__launch_bounds__(256)
__global__ void k_encoder(const float* __restrict__ obs, const _Float16* __restrict__ ench,
                          const _Float16* __restrict__ encl,
                          const float* __restrict__ encb, float* __restrict__ lstmin){
  __shared__ _Float16 Ah[128][40], Al[128][40], Bh[128][40], Bl[128][40];
  const int mt = blockIdx.x, nt = blockIdx.y;
  const int tid = threadIdx.x, w = tid >> 6, l = tid & 63;
  const int wm = (w >> 1)*64, wn = (w & 1)*64;
  const int m0 = mt*128, n0 = nt*128;
  f32x4 acc1[4][4], acc2[4][4];
  #pragma unroll
  for (int m = 0; m < 4; ++m)
    #pragma unroll
    for (int n = 0; n < 4; ++n)
      #pragma unroll
      for (int q = 0; q < 4; ++q){ acc1[m][n][q]=0.f; acc2[m][n][q]=0.f; }

  for (int k0 = 0; k0 < OBSD; k0 += 32){
    {
      int row = tid >> 1, c0 = (tid & 1)*16;
      const float* src = obs + (size_t)(m0+row)*OBSD + k0 + c0;
      #pragma unroll
      for (int cc = 0; cc < 16; ++cc){
        float v = src[cc];
        split1(v, Ah[row][c0+cc], Al[row][c0+cc]);
      }
      const _Float16* bh = ench + (size_t)(n0+row)*OBSD + k0 + c0;
      const _Float16* bl = encl + (size_t)(n0+row)*OBSD + k0 + c0;
      *(half8*)&Bh[row][c0]   = *(const half8*)(bh);
      *(half8*)&Bh[row][c0+8] = *(const half8*)(bh+8);
      *(half8*)&Bl[row][c0]   = *(const half8*)(bl);
      *(half8*)&Bl[row][c0+8] = *(const half8*)(bl+8);
    }
    __syncthreads();
    half8 ah[4], al[4], bh[4], bl[4];
    #pragma unroll
    for (int m = 0; m < 4; ++m){
      ah[m] = *(const half8*)&Ah[wm + m*16 + (l & 15)][(l >> 4)*8];
      al[m] = *(const half8*)&Al[wm + m*16 + (l & 15)][(l >> 4)*8];
    }
    #pragma unroll
    for (int n = 0; n < 4; ++n){
      bh[n] = *(const half8*)&Bh[wn + n*16 + (l & 15)][(l >> 4)*8];
      bl[n] = *(const half8*)&Bl[wn + n*16 + (l & 15)][(l >> 4)*8];
    }
    #pragma unroll
    for (int m = 0; m < 4; ++m)
      #pragma unroll
      for (int n = 0; n < 4; ++n){
        acc1[m][n] = __builtin_amdgcn_mfma_f32_16x16x32_f16(ah[m], bh[n], acc1[m][n], 0, 0, 0);
        acc2[m][n] = __builtin_amdgcn_mfma_f32_16x16x32_f16(ah[m], bl[n], acc2[m][n], 0, 0, 0);
        acc2[m][n] = __builtin_amdgcn_mfma_f32_16x16x32_f16(al[m], bh[n], acc2[m][n], 0, 0, 0);
      }
    __syncthreads();
  }
  #pragma unroll
  for (int m = 0; m < 4; ++m)
    #pragma unroll
    for (int n = 0; n < 4; ++n)
      #pragma unroll
      for (int q = 0; q < 4; ++q){
        int row = m0 + wm + m*16 + (l >> 4)*4 + q;
        int col = n0 + wn + n*16 + (l & 15);
        float v = acc1[m][n][q] + acc2[m][n][q]*INV_SCL + encb[col];
        lstmin[(size_t)row*DD + col] = fmaxf(v, 0.f);
      }
}

// ---------------- per-step LSTM layer kernel (fp16x3 split GEMM) ----------------
// gates = [p1 | p2*nd] @ W^T + bias ; pointwise LSTM update in fp32.
// grid = 132 blocks: mt = bid&3 (64-row M tile), js = bid>>2 (16-wide hidden strip)
__launch_bounds__(256)
__global__ void k_step(const float* __restrict__ p1, const float* __restrict__ p2,
                       const int* __restrict__ term,
                       const _Float16* __restrict__ Wh, const _Float16* __restrict__ Wl,
                       const float* __restrict__ bias, float* __restrict__ cst,
                       float* __restrict__ hout, float* __restrict__ outs){
  __shared__ _Float16 Ah[64][40], Al[64][40], Bh[64][40], Bl[64][40];
  const int bid = blockIdx.x;
  const int mt = bid & 3, js = bid >> 2;
  const int tid = threadIdx.x, w = tid >> 6, l = tid & 63;
  const int m0 = mt*64, j0 = js*16;

  const int arow = tid >> 2, ac0 = (tid & 3)*8;
  const int abrow = m0 + arow;
  const int wrow = (arow >> 4)*DD + j0 + (arow & 15);
  const float amask = (term[abrow] != 0) ? 0.f : 1.f;

  float av[8];
  half8 vbh, vbl;

  auto loadA = [&](int it){
    int col = it*32 + ac0;
    float msk = 1.f;
    const float* src;
    if (col < DD) src = p1 + (size_t)abrow*DD + col;
    else { src = p2 + (size_t)abrow*DD + (col - DD); msk = amask; }
    float4 f0 = *(const float4*)src;
    float4 f1 = *(const float4*)(src+4);
    av[0]=f0.x*msk; av[1]=f0.y*msk; av[2]=f0.z*msk; av[3]=f0.w*msk;
    av[4]=f1.x*msk; av[5]=f1.y*msk; av[6]=f1.z*msk; av[7]=f1.w*msk;
  };
  auto loadB = [&](int it){
    size_t off = (size_t)wrow*KK + it*32 + ac0;
    vbh = *(const half8*)(Wh + off);
    vbl = *(const half8*)(Wl + off);
  };

  f32x4 acc1[4], acc2[4];
  #pragma unroll
  for (int g = 0; g < 4; ++g)
    #pragma unroll
    for (int q = 0; q < 4; ++q){ acc1[g][q]=0.f; acc2[g][q]=0.f; }

  loadA(0); loadB(0);
  for (int it = 0; it < 33; ++it){
    {
      half8 hh, ll;
      #pragma unroll
      for (int j = 0; j < 8; ++j){ _Float16 h, lo; split1(av[j], h, lo); hh[j]=h; ll[j]=lo; }
      *(half8*)&Ah[arow][ac0] = hh;
      *(half8*)&Al[arow][ac0] = ll;
      *(half8*)&Bh[arow][ac0] = vbh;
      *(half8*)&Bl[arow][ac0] = vbl;
    }
    __syncthreads();
    if (it < 32){ loadA(it+1); loadB(it+1); }   // prefetch overlaps MFMA below
    half8 fah = *(const half8*)&Ah[w*16 + (l & 15)][(l >> 4)*8];
    half8 fal = *(const half8*)&Al[w*16 + (l & 15)][(l >> 4)*8];
    #pragma unroll
    for (int g = 0; g < 4; ++g){
      half8 fbh = *(const half8*)&Bh[g*16 + (l & 15)][(l >> 4)*8];
      half8 fbl = *(const half8*)&Bl[g*16 + (l & 15)][(l >> 4)*8];
      acc1[g] = __builtin_amdgcn_mfma_f32_16x16x32_f16(fah, fbh, acc1[g], 0, 0, 0);
      acc2[g] = __builtin_amdgcn_mfma_f32_16x16x32_f16(fah, fbl, acc2[g], 0, 0, 0);
      acc2[g] = __builtin_amdgcn_mfma_f32_16x16x32_f16(fal, fbh, acc2[g], 0, 0, 0);
    }
    __syncthreads();
  }

  const int j = j0 + (l & 15);
  #pragma unroll
  for (int q = 0; q < 4; ++q){
    int brow = m0 + w*16 + (l >> 4)*4 + q;
    float iv = acc1[0][q] + acc2[0][q]*INV_SCL + bias[0*DD + j];
    float fv = acc1[1][q] + acc2[1][q]*INV_SCL + bias[1*DD + j];
    float gv = acc1[2][q] + acc2[2][q]*INV_SCL + bias[2*DD + j];
    float ov = acc1[3][q] + acc2[3][q]*INV_SCL + bias[3*DD + j];
    float cp = cst[(size_t)brow*DD + j];
    if (term[brow] != 0) cp = 0.f;
    float cn = sigf(fv)*cp + sigf(iv)*tanhf(gv);
    float hn = sigf(ov)*tanhf(cn);
    cst[(size_t)brow*DD + j] = cn;
    hout[(size_t)brow*DD + j] = hn;
    if (outs) outs[(size_t)brow*DD + j] = hn;
  }
}

// ---------------- heads: logits/baseline/action ----------------
// grid = 256 blocks x 128 rows. N=16 (15 logits + baseline). argmax over a<15.
__launch_bounds__(256)
__global__ void k_heads(const float* __restrict__ outs,
                        const float* __restrict__ polw, const float* __restrict__ basew,
                        const float* __restrict__ polb, const float* __restrict__ baseb,
                        float* __restrict__ dout){
  __shared__ _Float16 Ah[128][40], Al[128][40];
  __shared__ _Float16 Bh[16][552], Bl[16][552];
  const int bid = blockIdx.x;
  const int tid = threadIdx.x, w = tid >> 6, l = tid & 63;
  const int m0 = bid*128;

  for (int i = tid; i < 16*544; i += 256){
    int r = i / 544, c = i % 544;
    float v = 0.f;
    if (c < DD) v = (r < NA) ? polw[r*DD + c] : basew[c];
    split1(v, Bh[r][c], Bl[r][c]);
  }
  __syncthreads();

  f32x4 acc1[2], acc2[2];
  #pragma unroll
  for (int m = 0; m < 2; ++m)
    #pragma unroll
    for (int q = 0; q < 4; ++q){ acc1[m][q]=0.f; acc2[m][q]=0.f; }

  for (int it = 0; it < 17; ++it){
    const int k0 = it*32;
    {
      int row = tid >> 1, c0 = (tid & 1)*16;
      const float* src = outs + (size_t)(m0+row)*DD + k0 + c0;   // overreads into pad; B=0 there
      #pragma unroll
      for (int cc = 0; cc < 16; ++cc)
        split1(src[cc], Ah[row][c0+cc], Al[row][c0+cc]);
    }
    __syncthreads();
    half8 fbh = *(const half8*)&Bh[l & 15][k0 + (l >> 4)*8];
    half8 fbl = *(const half8*)&Bl[l & 15][k0 + (l >> 4)*8];
    #pragma unroll
    for (int m = 0; m < 2; ++m){
      half8 fah = *(const half8*)&Ah[w*32 + m*16 + (l & 15)][(l >> 4)*8];
      half8 fal = *(const half8*)&Al[w*32 + m*16 + (l & 15)][(l >> 4)*8];
      acc1[m] = __builtin_amdgcn_mfma_f32_16x16x32_f16(fah, fbh, acc1[m], 0, 0, 0);
      acc2[m] = __builtin_amdgcn_mfma_f32_16x16x32_f16(fah, fbl, acc2[m], 0, 0, 0);
      acc2[m] = __builtin_amdgcn_mfma_f32_16x16x32_f16(fal, fbh, acc2[m], 0, 0, 0);
    }
    __syncthreads();
  }

  const int a = l & 15;
  const size_t base_off = (size_t)TT*BB*NA;
  const size_t act_off  = base_off + (size_t)TT*BB;
  #pragma unroll
  for (int m = 0; m < 2; ++m)
    #pragma unroll
    for (int q = 0; q < 4; ++q){
      int r = m0 + w*32 + m*16 + (l >> 4)*4 + q;
      float v = acc1[m][q] + acc2[m][q]*INV_SCL + ((a < NA) ? polb[a] : baseb[0]);
      float key = (a < NA) ? v : -3.4e38f;
      int ki = a;
      #pragma unroll
      for (int s = 1; s < 16; s <<= 1){
        float ov = __shfl_xor(key, s, 64);
        int   oi = __shfl_xor(ki,  s, 64);
        if (ov > key || (ov == key && oi < ki)){ key = ov; ki = oi; }
      }
      if (a < NA) dout[(size_t)r*NA + a] = v;
      if (a == NA) dout[base_off + r] = v;
      if (a == 0)  dout[act_off + r] = (float)ki;
    }
}

// ---------------- launch ----------------
extern "C" void kernel_launch(void* const* d_in, const int* in_sizes, int n_in,
                              void* d_out, int out_size, void* d_ws, size_t ws_size,
                              hipStream_t stream){
  const float* obs        = (const float*)d_in[0];
  const int*   last_act   = (const int*)  d_in[1];
  const float* reward     = (const float*)d_in[2];
  const int*   terminated = (const int*)  d_in[3];
  const float* enc_w      = (const float*)d_in[4];
  const float* enc_b      = (const float*)d_in[5];
  const float* w_ih0      = (const float*)d_in[6];
  const float* w_hh0      = (const float*)d_in[7];
  const float* b_ih0      = (const float*)d_in[8];
  const float* b_hh0      = (const float*)d_in[9];
  const float* w_ih1      = (const float*)d_in[10];
  const float* w_hh1      = (const float*)d_in[11];
  const float* b_ih1      = (const float*)d_in[12];
  const float* b_hh1      = (const float*)d_in[13];
  const float* pol_w      = (const float*)d_in[14];
  const float* pol_b      = (const float*)d_in[15];
  const float* base_w     = (const float*)d_in[16];
  const float* base_b     = (const float*)d_in[17];

  char* ws = (char*)d_ws;
  size_t o = 0;
  auto alloc = [&](size_t bytes){ size_t r = o; o += (bytes + 255) & ~(size_t)255; return r; };

  _Float16* Wh0   = (_Float16*)(ws + alloc((size_t)GG*KK*2));
  _Float16* Wl0   = (_Float16*)(ws + alloc((size_t)GG*KK*2));
  _Float16* Wh1   = (_Float16*)(ws + alloc((size_t)GG*KK*2));
  _Float16* Wl1   = (_Float16*)(ws + alloc((size_t)GG*KK*2));
  float* bias0    = (float*)(ws + alloc((size_t)GG*4));
  float* bias1    = (float*)(ws + alloc((size_t)GG*4));
  _Float16* ench  = (_Float16*)(ws + alloc((size_t)FEATD*OBSD*2));
  _Float16* encl  = (_Float16*)(ws + alloc((size_t)FEATD*OBSD*2));
  // fp32 lstm_in; after step t consumes row-block t, layer-1 h2 overwrites it (outs alias)
  float* lstm_in  = (float*)(ws + alloc((size_t)TT*BB*DD*4 + 4096));
  char*  states   = ws + o;
  float* h1a      = (float*)(ws + alloc((size_t)BB*DD*4));
  float* h1b      = (float*)(ws + alloc((size_t)BB*DD*4));
  float* h2a      = (float*)(ws + alloc((size_t)BB*DD*4));
  float* h2b      = (float*)(ws + alloc((size_t)BB*DD*4));
  float* c1       = (float*)(ws + alloc((size_t)BB*DD*4));
  float* c2       = (float*)(ws + alloc((size_t)BB*DD*4));
  size_t state_bytes = (size_t)(ws + o - states);

  hipMemsetAsync(states, 0, state_bytes, stream);

  k_prep_w<<<2048, 256, 0, stream>>>(w_ih0, w_hh0, b_ih0, b_hh0, Wh0, Wl0, bias0);
  k_prep_w<<<2048, 256, 0, stream>>>(w_ih1, w_hh1, b_ih1, b_hh1, Wh1, Wl1, bias1);
  k_conv_encw<<<2048, 256, 0, stream>>>(enc_w, ench, encl);
  k_fill_extra<<<TT*BB/256, 256, 0, stream>>>(reward, last_act, lstm_in);

  dim3 eg(TT*BB/128, FEATD/128);
  k_encoder<<<eg, 256, 0, stream>>>(obs, ench, encl, enc_b, lstm_in);

  float* h1[2] = {h1a, h1b};
  float* h2[2] = {h2a, h2b};
  for (int t = 0; t < TT; ++t){
    int cur = t & 1, nxt = cur ^ 1;
    k_step<<<132, 256, 0, stream>>>(lstm_in + (size_t)t*BB*DD, h1[cur],
                                    terminated + (size_t)t*BB, Wh0, Wl0, bias0,
                                    c1, h1[nxt], (float*)nullptr);
    k_step<<<132, 256, 0, stream>>>(h1[nxt], h2[cur],
                                    terminated + (size_t)t*BB, Wh1, Wl1, bias1,
                                    c2, h2[nxt], lstm_in + (size_t)t*BB*DD);
  }

  k_heads<<<TT*BB/128, 256, 0, stream>>>(lstm_in, pol_w, base_w, pol_b, base_b, (float*)d_out);
}